// Round 9
// baseline (747.558 us; speedup 1.0000x reference)
//
#include <hip/hip_runtime.h>
#include <hip/hip_bf16.h>
#include <math.h>

#define N_NODES 100000
#define N_EDGES 800000
#define H 256
#define NTYPES 22
#define SCAN_G 98                        // ceil(100000/1024)
#define GRID5 ((N_NODES + 127) / 128)    // 782 blocks of BM=128

typedef __attribute__((ext_vector_type(8))) short short8;
typedef __attribute__((ext_vector_type(4))) float f32x4;
typedef unsigned short u16;

__device__ __forceinline__ u16 f2bf(float f) {
    unsigned u = __float_as_uint(f);
    u += 0x7FFF + ((u >> 16) & 1);      // RNE
    return (u16)(u >> 16);
}
__device__ __forceinline__ float bf2f(u16 u) {
    return __uint_as_float(((unsigned)u) << 16);
}
// sigma^-1: memcol -> logical col (K-row permutation of weights)
__device__ __forceinline__ int pi2(int k) {
    return (k & 192) | ((k & 3) << 4) | ((k >> 2) & 15);
}

// ---------------------------------------------------------------------------
// conv: clause fp32 -> bf16 (logical col order), fully coalesced
// ---------------------------------------------------------------------------
__global__ __launch_bounds__(256) void conv_bf16(
    const float* __restrict__ src, u16* __restrict__ dst)
{
    size_t i = (size_t)blockIdx.x * 256 + threadIdx.x;   // one per 8 elems
    const float4 a = ((const float4*)src)[i * 2];
    const float4 b = ((const float4*)src)[i * 2 + 1];
    short8 v;
    v[0] = (short)f2bf(a.x); v[1] = (short)f2bf(a.y);
    v[2] = (short)f2bf(a.z); v[3] = (short)f2bf(a.w);
    v[4] = (short)f2bf(b.x); v[5] = (short)f2bf(b.y);
    v[6] = (short)f2bf(b.z); v[7] = (short)f2bf(b.w);
    ((short8*)dst)[i] = v;
}

// ---------------------------------------------------------------------------
// prep_small: C1 = temp_W @ W1b (32x256), C2 = emb @ W1c (22x256),
// beff = fus_b1 + temp_b @ W1b (256)   (all logical order, fp32)
// ---------------------------------------------------------------------------
__global__ __launch_bounds__(256) void prep_small(
    const float* __restrict__ temp_W, const float* __restrict__ temp_b,
    const float* __restrict__ emb, const float* __restrict__ fus_W1,
    const float* __restrict__ fus_b1,
    float* __restrict__ C1, float* __restrict__ C2, float* __restrict__ beff)
{
    int b = blockIdx.x;
    int j = threadIdx.x;
    if (b < 32) {
        float acc = 0.f;
        #pragma unroll 8
        for (int m = 0; m < H; ++m)
            acc += temp_W[b * H + m] * fus_W1[(size_t)(H + m) * H + j];
        C1[b * H + j] = acc;
    } else if (b < 32 + NTYPES) {
        int e = b - 32;
        float acc = 0.f;
        #pragma unroll 8
        for (int m = 0; m < H; ++m)
            acc += emb[e * H + m] * fus_W1[(size_t)(2 * H + m) * H + j];
        C2[e * H + j] = acc;
    } else {
        float acc = fus_b1[j];
        #pragma unroll 8
        for (int m = 0; m < H; ++m)
            acc += temp_b[m] * fus_W1[(size_t)(H + m) * H + j];
        beff[j] = acc;
    }
}

// ---------------------------------------------------------------------------
// prep_frag: pack weights into MFMA B-fragment order, bf16.
// Blob: kstep s (49) x chunk c (1024) x 8 bf16; c = nt*64+l ->
// W col = nt*16+(l&15), k_in_step = 8*(l>>4)+i.
// s0..7 fus_W1 clause part (logical K), s8 C1 (logical), s9..16 fus_W2 (pi2),
// s17..32 deriv_W[0], s33..48 deriv_W[1] (pi2 within each 256-half).
// ---------------------------------------------------------------------------
__global__ __launch_bounds__(256) void prep_frag(
    const float* __restrict__ fus_W1, const float* __restrict__ C1,
    const float* __restrict__ fus_W2, const float* __restrict__ deriv_W,
    u16* __restrict__ wblob)
{
    int s = blockIdx.x;
    #pragma unroll
    for (int it = 0; it < 4; ++it) {
        int c = it * 256 + threadIdx.x;
        int l = c & 63, nt = c >> 6;
        int ncol = (nt << 4) | (l & 15);
        int kin = (l >> 4) << 3;
        short8 v;
        #pragma unroll
        for (int i = 0; i < 8; ++i) {
            const float* srcp;
            if (s < 8) {
                srcp = fus_W1 + (size_t)(s * 32 + kin + i) * H;
            } else if (s == 8) {
                srcp = C1 + (size_t)(kin + i) * H;
            } else if (s < 17) {
                int k = (s - 9) * 32 + kin + i;
                srcp = fus_W2 + (size_t)pi2(k) * H;
            } else if (s < 33) {
                int k = (s - 17) * 32 + kin + i;
                srcp = deriv_W + (size_t)((k >> 8) * 256 + pi2(k & 255)) * H;
            } else {
                int k = (s - 33) * 32 + kin + i;
                srcp = deriv_W + (size_t)(512 + (k >> 8) * 256 + pi2(k & 255)) * H;
            }
            v[i] = (short)f2bf(srcp[ncol]);
        }
        *reinterpret_cast<short8*>(wblob + (size_t)s * 8192 + (size_t)c * 8) = v;
    }
}

// ---------------------------------------------------------------------------
// CSR build
// ---------------------------------------------------------------------------
__global__ void count_kernel(const int* __restrict__ dst, int* __restrict__ cnt)
{
    int e = blockIdx.x * blockDim.x + threadIdx.x;
    if (e < N_EDGES) atomicAdd(&cnt[dst[e]], 1);
}

__global__ __launch_bounds__(1024) void scan1_kernel(
    const int* __restrict__ cnt, int* __restrict__ off, int* __restrict__ bsum)
{
    __shared__ int s[1024];
    int i = blockIdx.x * 1024 + threadIdx.x;
    int v = (i < N_NODES) ? cnt[i] : 0;
    s[threadIdx.x] = v;
    __syncthreads();
    #pragma unroll
    for (int o = 1; o < 1024; o <<= 1) {
        int t = (threadIdx.x >= o) ? s[threadIdx.x - o] : 0;
        __syncthreads();
        s[threadIdx.x] += t;
        __syncthreads();
    }
    if (i < N_NODES) off[i] = s[threadIdx.x];
    if (threadIdx.x == 1023) bsum[blockIdx.x] = s[1023];
}

__global__ void scan2_kernel(const int* __restrict__ bsum, int* __restrict__ bbase)
{
    if (threadIdx.x == 0) {
        int acc = 0;
        for (int b = 0; b < SCAN_G; ++b) { bbase[b] = acc; acc += bsum[b]; }
    }
}

__global__ __launch_bounds__(1024) void scan3_kernel(
    int* __restrict__ off, const int* __restrict__ bbase,
    const int* __restrict__ cnt, int* __restrict__ cursor)
{
    int i = blockIdx.x * 1024 + threadIdx.x;
    if (i < N_NODES) {
        int incl = off[i] + bbase[blockIdx.x];
        off[i] = incl;
        cursor[i] = incl - cnt[i];
    }
}

__global__ void fill_kernel(const int* __restrict__ src, const int* __restrict__ dst,
                            int* __restrict__ cursor, int* __restrict__ csr)
{
    int e = blockIdx.x * blockDim.x + threadIdx.x;
    if (e < N_EDGES) {
        int pos = atomicAdd(&cursor[dst[e]], 1);
        csr[pos] = src[e];
    }
}

// ---------------------------------------------------------------------------
// gather: one wave per node, half-wave per edge-stream
// ---------------------------------------------------------------------------
__global__ __launch_bounds__(256) void gather_kernel(
    const u16* __restrict__ xb, const int* __restrict__ csr,
    const int* __restrict__ off, const int* __restrict__ cnt,
    u16* __restrict__ agg)
{
    int node = blockIdx.x * 4 + (threadIdx.x >> 6);
    int l = threadIdx.x & 63;
    int half = l >> 5, lc = l & 31;
    int deg = cnt[node];
    int start = off[node] - deg;
    float a[8] = {0.f, 0.f, 0.f, 0.f, 0.f, 0.f, 0.f, 0.f};
    int j = half;
    for (; j + 2 < deg; j += 4) {
        int s0 = csr[start + j];
        int s1 = csr[start + j + 2];
        short8 v0 = *reinterpret_cast<const short8*>(xb + (size_t)s0 * H + lc * 8);
        short8 v1 = *reinterpret_cast<const short8*>(xb + (size_t)s1 * H + lc * 8);
        #pragma unroll
        for (int i = 0; i < 8; ++i)
            a[i] += bf2f((u16)v0[i]) + bf2f((u16)v1[i]);
    }
    if (j < deg) {
        int s0 = csr[start + j];
        short8 v0 = *reinterpret_cast<const short8*>(xb + (size_t)s0 * H + lc * 8);
        #pragma unroll
        for (int i = 0; i < 8; ++i)
            a[i] += bf2f((u16)v0[i]);
    }
    #pragma unroll
    for (int i = 0; i < 8; ++i)
        a[i] += __shfl_xor(a[i], 32);
    if (half == 0) {
        float sc = 1.0f / fmaxf((float)deg, 1.0f);
        short8 o;
        #pragma unroll
        for (int i = 0; i < 8; ++i) o[i] = (short)f2bf(a[i] * sc);
        *reinterpret_cast<short8*>(agg + (size_t)node * H + lc * 8) = o;
    }
}

// ---------------------------------------------------------------------------
// Zero-LDS MFMA GEMM: A and B fragments loaded global->register directly.
// A-frag: 16B/lane dwordx4 (16 fully-consumed lines/instr, L1 reuse x4 wn).
// B-frag: 1KB/instr contiguous from fragment-packed wblob (L2-resident).
// No staging barriers; waves free-run; LN epilogue uses a 4KB red buffer.
// 8 waves (wm=w>>2, wn=w&3), BM=128, BN=256.
// ---------------------------------------------------------------------------
__device__ __forceinline__ void mfma_regs(const short8 a[4], const short8 b[4],
                                          f32x4 acc[4][4])
{
    #pragma unroll
    for (int n = 0; n < 4; ++n)
        #pragma unroll
        for (int m = 0; m < 4; ++m)
            acc[m][n] = __builtin_amdgcn_mfma_f32_16x16x32_bf16(a[m], b[n],
                                                                acc[m][n], 0, 0, 0);
}

// ---------------------------------------------------------------------------
// K1: h = relu(clause@W1a + pe@C1 + C2[type] + beff); h sigma-ordered bf16.
// ---------------------------------------------------------------------------
__global__ __launch_bounds__(512, 4) void k1_mfma(
    const u16* __restrict__ cb, const float* __restrict__ ts,
    const int* __restrict__ types, const u16* __restrict__ wblob,
    const float* __restrict__ C2, const float* __restrict__ beff,
    u16* __restrict__ hb)
{
    int tid = threadIdx.x, w = tid >> 6, l = tid & 63;
    int wm = w >> 2, wn = w & 3, g = l >> 4, c0 = l & 15;
    int i0 = blockIdx.x * 128;

    int rows[4];
    size_t rowo[4];
    #pragma unroll
    for (int m = 0; m < 4; ++m) {
        rows[m] = min(i0 + ((((wm << 2) | m) << 4) | c0), N_NODES - 1);
        rowo[m] = (size_t)rows[m] * H;
    }
    const u16* wb = wblob + ((((wn << 2) << 6) | l) << 3);
    int kg = g << 3;

    f32x4 acc[4][4] = {};
    #pragma unroll
    for (int t = 0; t < 8; ++t) {
        short8 a[4], b[4];
        #pragma unroll
        for (int m = 0; m < 4; ++m)
            a[m] = *reinterpret_cast<const short8*>(cb + rowo[m] + t * 32 + kg);
        #pragma unroll
        for (int n = 0; n < 4; ++n)
            b[n] = *reinterpret_cast<const short8*>(wb + (size_t)t * 8192 + n * 512);
        mfma_regs(a, b, acc);
    }
    // pe k-step (t=8): compute per-lane fragment in registers
    {
        short8 a[4], b[4];
        #pragma unroll
        for (int m = 0; m < 4; ++m) {
            float tsv = ts[rows[m]];
            short8 v;
            #pragma unroll
            for (int i = 0; i < 8; ++i) {
                int k = kg + i;
                float fr = expf(-0.57564627324851f * (float)(k & 15));
                float ang = tsv * fr;
                v[i] = (short)f2bf((k < 16) ? sinf(ang) : cosf(ang));
            }
            a[m] = v;
        }
        #pragma unroll
        for (int n = 0; n < 4; ++n)
            b[n] = *reinterpret_cast<const short8*>(wb + (size_t)8 * 8192 + n * 512);
        mfma_regs(a, b, acc);
    }

    float bev[4];
    #pragma unroll
    for (int n = 0; n < 4; ++n) bev[n] = beff[(((wn << 2) | n) << 4) | c0];
    #pragma unroll
    for (int m = 0; m < 4; ++m) {
        #pragma unroll
        for (int r = 0; r < 4; ++r) {
            int rl = (((wm << 2) | m) << 4) + (g << 2) + r;
            int row = i0 + rl;
            bool ok = row < N_NODES;
            int tp = types[ok ? row : 0];
            const float* c2r = C2 + (size_t)tp * H;
            ushort4 o;
            float v0 = fmaxf(acc[m][0][r] + bev[0] + c2r[((wn << 2) << 4) | c0], 0.f);
            float v1 = fmaxf(acc[m][1][r] + bev[1] + c2r[(((wn << 2) | 1) << 4) | c0], 0.f);
            float v2 = fmaxf(acc[m][2][r] + bev[2] + c2r[(((wn << 2) | 2) << 4) | c0], 0.f);
            float v3 = fmaxf(acc[m][3][r] + bev[3] + c2r[(((wn << 2) | 3) << 4) | c0], 0.f);
            o.x = f2bf(v0); o.y = f2bf(v1); o.z = f2bf(v2); o.w = f2bf(v3);
            if (ok)
                *reinterpret_cast<ushort4*>(hb + (size_t)row * H + (wn << 6) + (c0 << 2)) = o;
        }
    }
}

// ---------------------------------------------------------------------------
// K2: xb = bf16(LN(h@W2 + b2 + clause) * g + b); in-place hb==xb allowed
// (each block reads only its own rows).
// ---------------------------------------------------------------------------
__global__ __launch_bounds__(512, 4) void k2_mfma(
    const u16* __restrict__ hb, const u16* __restrict__ cb,
    const u16* __restrict__ wblob, const float* __restrict__ b2,
    const float* __restrict__ gW, const float* __restrict__ bW,
    u16* __restrict__ xb)
{
    __shared__ float2 red[512];
    int tid = threadIdx.x, w = tid >> 6, l = tid & 63;
    int wm = w >> 2, wn = w & 3, g = l >> 4, c0 = l & 15;
    int i0 = blockIdx.x * 128;

    size_t rowo[4];
    #pragma unroll
    for (int m = 0; m < 4; ++m)
        rowo[m] = (size_t)min(i0 + ((((wm << 2) | m) << 4) | c0), N_NODES - 1) * H;
    const u16* wb = wblob + ((((wn << 2) << 6) | l) << 3);
    int kg = g << 3;

    f32x4 acc[4][4] = {};
    #pragma unroll
    for (int t = 0; t < 8; ++t) {
        short8 a[4], b[4];
        #pragma unroll
        for (int m = 0; m < 4; ++m)
            a[m] = *reinterpret_cast<const short8*>(hb + rowo[m] + t * 32 + kg);
        #pragma unroll
        for (int n = 0; n < 4; ++n)
            b[n] = *reinterpret_cast<const short8*>(wb + (size_t)t * 8192 + n * 512);
        mfma_regs(a, b, acc);
    }

    float bv[4], gv[4], bbv[4];
    int lc[4];
    #pragma unroll
    for (int n = 0; n < 4; ++n) {
        lc[n] = (((wn << 2) | n) << 4) | c0;
        bv[n] = b2[lc[n]]; gv[n] = gW[lc[n]]; bbv[n] = bW[lc[n]];
    }
    #pragma unroll
    for (int m = 0; m < 4; ++m) {
        #pragma unroll
        for (int r = 0; r < 4; ++r) {
            int rl = (((wm << 2) | m) << 4) + (g << 2) + r;
            int rowc = min(i0 + rl, N_NODES - 1);
            const u16* cr = cb + (size_t)rowc * H;   // logical order
            float s = 0.f, q = 0.f;
            #pragma unroll
            for (int n = 0; n < 4; ++n) {
                float pv = acc[m][n][r] + bv[n] + bf2f(cr[lc[n]]);
                acc[m][n][r] = pv;
                s += pv; q += pv * pv;
            }
            #pragma unroll
            for (int o = 1; o < 16; o <<= 1) {
                s += __shfl_xor(s, o);
                q += __shfl_xor(q, o);
            }
            if (c0 == 0) red[(rl << 2) | wn] = make_float2(s, q);
        }
    }
    __syncthreads();
    #pragma unroll
    for (int m = 0; m < 4; ++m) {
        #pragma unroll
        for (int r = 0; r < 4; ++r) {
            int rl = (((wm << 2) | m) << 4) + (g << 2) + r;
            int row = i0 + rl;
            float2 t0 = red[(rl << 2) | 0], t1 = red[(rl << 2) | 1];
            float2 t2 = red[(rl << 2) | 2], t3 = red[(rl << 2) | 3];
            float S = t0.x + t1.x + t2.x + t3.x;
            float Q = t0.y + t1.y + t2.y + t3.y;
            float mu = S * (1.0f / 256.0f);
            float rstd = rsqrtf(Q * (1.0f / 256.0f) - mu * mu + 1e-5f);
            if (row < N_NODES) {
                ushort4 o;
                o.x = f2bf((acc[m][0][r] - mu) * rstd * gv[0] + bbv[0]);
                o.y = f2bf((acc[m][1][r] - mu) * rstd * gv[1] + bbv[1]);
                o.z = f2bf((acc[m][2][r] - mu) * rstd * gv[2] + bbv[2]);
                o.w = f2bf((acc[m][3][r] - mu) * rstd * gv[3] + bbv[3]);
                *reinterpret_cast<ushort4*>(xb + (size_t)row * H + (wn << 6) + (c0 << 2)) = o;
            }
        }
    }
}

// ---------------------------------------------------------------------------
// K5: x' = LN(x + relu([x|agg]@Wl + bl))*g + b; in-place on xb.
// FINAL writes fp32 d_out in logical column order.
// ---------------------------------------------------------------------------
template<bool FINAL>
__global__ __launch_bounds__(512, 4) void k5_mfma(
    const u16* __restrict__ xb, const u16* __restrict__ aggb,
    const u16* __restrict__ wblob, const float* __restrict__ bl,
    const float* __restrict__ gl_, const float* __restrict__ bnl,
    u16* __restrict__ xbout, float* __restrict__ xout)
{
    __shared__ float2 red[512];
    int tid = threadIdx.x, w = tid >> 6, l = tid & 63;
    int wm = w >> 2, wn = w & 3, g = l >> 4, c0 = l & 15;
    int i0 = blockIdx.x * 128;

    size_t rowo[4];
    #pragma unroll
    for (int m = 0; m < 4; ++m)
        rowo[m] = (size_t)min(i0 + ((((wm << 2) | m) << 4) | c0), N_NODES - 1) * H;
    const u16* wb = wblob + ((((wn << 2) << 6) | l) << 3);
    int kg = g << 3;

    f32x4 acc[4][4] = {};
    #pragma unroll
    for (int t = 0; t < 16; ++t) {
        const u16* Ab = (t < 8) ? xb : aggb;
        int ko = (t & 7) * 32 + kg;
        short8 a[4], b[4];
        #pragma unroll
        for (int m = 0; m < 4; ++m)
            a[m] = *reinterpret_cast<const short8*>(Ab + rowo[m] + ko);
        #pragma unroll
        for (int n = 0; n < 4; ++n)
            b[n] = *reinterpret_cast<const short8*>(wb + (size_t)t * 8192 + n * 512);
        mfma_regs(a, b, acc);
    }

    float bv[4], gv[4], bbv[4];
    int lc[4];
    #pragma unroll
    for (int n = 0; n < 4; ++n) {
        lc[n] = (((wn << 2) | n) << 4) | c0;
        bv[n] = bl[lc[n]]; gv[n] = gl_[lc[n]]; bbv[n] = bnl[lc[n]];
    }
    #pragma unroll
    for (int m = 0; m < 4; ++m) {
        #pragma unroll
        for (int r = 0; r < 4; ++r) {
            int rl = (((wm << 2) | m) << 4) + (g << 2) + r;
            int rowc = min(i0 + rl, N_NODES - 1);
            ushort4 xr = *reinterpret_cast<const ushort4*>(
                xb + (size_t)rowc * H + (wn << 6) + (c0 << 2));
            float p0 = bf2f(xr.x) + fmaxf(acc[m][0][r] + bv[0], 0.f);
            float p1 = bf2f(xr.y) + fmaxf(acc[m][1][r] + bv[1], 0.f);
            float p2 = bf2f(xr.z) + fmaxf(acc[m][2][r] + bv[2], 0.f);
            float p3 = bf2f(xr.w) + fmaxf(acc[m][3][r] + bv[3], 0.f);
            acc[m][0][r] = p0; acc[m][1][r] = p1;
            acc[m][2][r] = p2; acc[m][3][r] = p3;
            float s = p0 + p1 + p2 + p3;
            float q = p0 * p0 + p1 * p1 + p2 * p2 + p3 * p3;
            #pragma unroll
            for (int o = 1; o < 16; o <<= 1) {
                s += __shfl_xor(s, o);
                q += __shfl_xor(q, o);
            }
            if (c0 == 0) red[(rl << 2) | wn] = make_float2(s, q);
        }
    }
    __syncthreads();
    #pragma unroll
    for (int m = 0; m < 4; ++m) {
        #pragma unroll
        for (int r = 0; r < 4; ++r) {
            int rl = (((wm << 2) | m) << 4) + (g << 2) + r;
            int row = i0 + rl;
            float2 t0 = red[(rl << 2) | 0], t1 = red[(rl << 2) | 1];
            float2 t2 = red[(rl << 2) | 2], t3 = red[(rl << 2) | 3];
            float S = t0.x + t1.x + t2.x + t3.x;
            float Q = t0.y + t1.y + t2.y + t3.y;
            float mu = S * (1.0f / 256.0f);
            float rstd = rsqrtf(Q * (1.0f / 256.0f) - mu * mu + 1e-5f);
            if (row < N_NODES) {
                if (FINAL) {
                    #pragma unroll
                    for (int n = 0; n < 4; ++n)
                        xout[(size_t)row * H + lc[n]] =
                            (acc[m][n][r] - mu) * rstd * gv[n] + bbv[n];
                } else {
                    ushort4 o;
                    o.x = f2bf((acc[m][0][r] - mu) * rstd * gv[0] + bbv[0]);
                    o.y = f2bf((acc[m][1][r] - mu) * rstd * gv[1] + bbv[1]);
                    o.z = f2bf((acc[m][2][r] - mu) * rstd * gv[2] + bbv[2]);
                    o.w = f2bf((acc[m][3][r] - mu) * rstd * gv[3] + bbv[3]);
                    *reinterpret_cast<ushort4*>(
                        xbout + (size_t)row * H + (wn << 6) + (c0 << 2)) = o;
                }
            }
        }
    }
}

// ---------------------------------------------------------------------------
extern "C" void kernel_launch(void* const* d_in, const int* in_sizes, int n_in,
                              void* d_out, int out_size, void* d_ws, size_t ws_size,
                              hipStream_t stream)
{
    const float* clause  = (const float*)d_in[0];
    const float* ts      = (const float*)d_in[1];
    const int*   types   = (const int*)  d_in[2];
    const int*   edges   = (const int*)  d_in[3];
    const float* emb     = (const float*)d_in[4];
    const float* temp_W  = (const float*)d_in[5];
    const float* temp_b  = (const float*)d_in[6];
    const float* fus_W1  = (const float*)d_in[7];
    const float* fus_b1  = (const float*)d_in[8];
    const float* fus_W2  = (const float*)d_in[9];
    const float* fus_b2  = (const float*)d_in[10];
    const float* in_g    = (const float*)d_in[11];
    const float* in_b    = (const float*)d_in[12];
    const float* deriv_W = (const float*)d_in[13];
    const float* deriv_b = (const float*)d_in[14];
    const float* dn_g    = (const float*)d_in[15];
    const float* dn_b    = (const float*)d_in[16];

    char* p = (char*)d_ws;
    float* C1   = (float*)p;            p += 32 * H * 4;
    float* C2   = (float*)p;            p += NTYPES * H * 4;
    float* beff = (float*)p;            p += H * 4;
    int* cnt    = (int*)p;              p += N_NODES * 4;
    int* off    = (int*)p;              p += N_NODES * 4;
    int* cursor = (int*)p;              p += N_NODES * 4;
    int* bsum   = (int*)p;              p += 128 * 4;
    int* bbase  = (int*)p;              p += 128 * 4;
    int* csr    = (int*)p;              p += N_EDGES * 4;
    u16* wblob  = (u16*)p;              p += 49 * 8192 * 2;
    u16* B1     = (u16*)p;              p += (size_t)N_NODES * H * 2;  // clause_bf / agg
    u16* B2     = (u16*)p;              p += (size_t)N_NODES * H * 2;  // h / xb
    float* x    = (float*)d_out;

    const int* src = edges;
    const int* dst = edges + N_EDGES;

    conv_bf16<<<(N_NODES * H / 8 + 255) / 256, 256, 0, stream>>>(clause, B1);
    prep_small<<<32 + NTYPES + 1, 256, 0, stream>>>(temp_W, temp_b, emb, fus_W1,
                                                    fus_b1, C1, C2, beff);
    prep_frag<<<49, 256, 0, stream>>>(fus_W1, C1, fus_W2, deriv_W, wblob);

    hipMemsetAsync(cnt, 0, N_NODES * sizeof(int), stream);
    count_kernel<<<(N_EDGES + 255) / 256, 256, 0, stream>>>(dst, cnt);
    scan1_kernel<<<SCAN_G, 1024, 0, stream>>>(cnt, off, bsum);
    scan2_kernel<<<1, 64, 0, stream>>>(bsum, bbase);
    scan3_kernel<<<SCAN_G, 1024, 0, stream>>>(off, bbase, cnt, cursor);
    fill_kernel<<<(N_EDGES + 255) / 256, 256, 0, stream>>>(src, dst, cursor, csr);

    k1_mfma<<<GRID5, 512, 0, stream>>>(B1, ts, types, wblob, C2, beff, B2);
    k2_mfma<<<GRID5, 512, 0, stream>>>(B2, B1, wblob + (size_t)9 * 8192,
                                       fus_b2, in_g, in_b, B2);

    // layer 0 (bf16 in-place on B2; B1 becomes agg)
    gather_kernel<<<N_NODES / 4, 256, 0, stream>>>(B2, csr, off, cnt, B1);
    k5_mfma<false><<<GRID5, 512, 0, stream>>>(
        B2, B1, wblob + (size_t)17 * 8192, deriv_b, dn_g, dn_b, B2, nullptr);
    // layer 1 (writes fp32 d_out, logical order)
    gather_kernel<<<N_NODES / 4, 256, 0, stream>>>(B2, csr, off, cnt, B1);
    k5_mfma<true><<<GRID5, 512, 0, stream>>>(
        B2, B1, wblob + (size_t)33 * 8192, deriv_b + H, dn_g + H, dn_b + H,
        nullptr, x);
}

// Round 10
// 532.414 us; speedup vs baseline: 1.4041x; 1.4041x over previous
//
#include <hip/hip_runtime.h>
#include <hip/hip_bf16.h>
#include <math.h>

#define N_NODES 100000
#define N_EDGES 800000
#define H 256
#define NTYPES 22
#define SCAN_G 98                        // ceil(100000/1024)
#define GRID5 ((N_NODES + 127) / 128)    // 782 blocks of BM=128

typedef __attribute__((ext_vector_type(8))) short short8;
typedef __attribute__((ext_vector_type(4))) float f32x4;
typedef unsigned short u16;

__device__ __forceinline__ u16 f2bf(float f) {
    unsigned u = __float_as_uint(f);
    u += 0x7FFF + ((u >> 16) & 1);      // RNE
    return (u16)(u >> 16);
}
__device__ __forceinline__ float bf2f(u16 u) {
    return __uint_as_float(((unsigned)u) << 16);
}
// sigma^-1: memcol -> logical col (K-row permutation of weights)
__device__ __forceinline__ int pi2(int k) {
    return (k & 192) | ((k & 3) << 4) | ((k >> 2) & 15);
}

// async global->LDS, 16B/lane; LDS dest = wave-uniform base + lane*16
__device__ __forceinline__ void gload16(const void* g, void* l) {
    __builtin_amdgcn_global_load_lds(
        (const __attribute__((address_space(1))) unsigned int*)g,
        (__attribute__((address_space(3))) unsigned int*)l, 16, 0, 0);
}

// Counted-vmcnt barrier pair (T3/T4): BAR_WAIT(N) = "stage(t) landed, newer
// prefetch stays in flight"; BAR_REL = read-release. sched_barrier(0) pins
// MFMAs (register-only ops can cross "memory" clobbers — rule #18).
#define BAR_WAIT3()  do { __builtin_amdgcn_sched_barrier(0); \
    asm volatile("s_waitcnt vmcnt(3)\ns_barrier" ::: "memory"); } while (0)
#define BAR_WAIT2()  do { __builtin_amdgcn_sched_barrier(0); \
    asm volatile("s_waitcnt vmcnt(2)\ns_barrier" ::: "memory"); } while (0)
#define BAR_WAIT0()  do { __builtin_amdgcn_sched_barrier(0); \
    asm volatile("s_waitcnt vmcnt(0)\ns_barrier" ::: "memory"); } while (0)
#define BAR_WAIT0L() do { __builtin_amdgcn_sched_barrier(0); \
    asm volatile("s_waitcnt vmcnt(0) lgkmcnt(0)\ns_barrier" ::: "memory"); } while (0)
#define BAR_REL()    do { __builtin_amdgcn_sched_barrier(0); \
    asm volatile("s_barrier" ::: "memory"); } while (0)

// ---------------------------------------------------------------------------
// conv: clause fp32 -> bf16 (logical col order), fully coalesced
// ---------------------------------------------------------------------------
__global__ __launch_bounds__(256) void conv_bf16(
    const float* __restrict__ src, u16* __restrict__ dst)
{
    size_t i = (size_t)blockIdx.x * 256 + threadIdx.x;   // one per 8 elems
    const float4 a = ((const float4*)src)[i * 2];
    const float4 b = ((const float4*)src)[i * 2 + 1];
    short8 v;
    v[0] = (short)f2bf(a.x); v[1] = (short)f2bf(a.y);
    v[2] = (short)f2bf(a.z); v[3] = (short)f2bf(a.w);
    v[4] = (short)f2bf(b.x); v[5] = (short)f2bf(b.y);
    v[6] = (short)f2bf(b.z); v[7] = (short)f2bf(b.w);
    ((short8*)dst)[i] = v;
}

// ---------------------------------------------------------------------------
// prep_small: C1 = temp_W @ W1b (32x256), C2 = emb @ W1c (22x256),
// beff = fus_b1 + temp_b @ W1b (256)   (all logical order, fp32)
// ---------------------------------------------------------------------------
__global__ __launch_bounds__(256) void prep_small(
    const float* __restrict__ temp_W, const float* __restrict__ temp_b,
    const float* __restrict__ emb, const float* __restrict__ fus_W1,
    const float* __restrict__ fus_b1,
    float* __restrict__ C1, float* __restrict__ C2, float* __restrict__ beff)
{
    int b = blockIdx.x;
    int j = threadIdx.x;
    if (b < 32) {
        float acc = 0.f;
        #pragma unroll 8
        for (int m = 0; m < H; ++m)
            acc += temp_W[b * H + m] * fus_W1[(size_t)(H + m) * H + j];
        C1[b * H + j] = acc;
    } else if (b < 32 + NTYPES) {
        int e = b - 32;
        float acc = 0.f;
        #pragma unroll 8
        for (int m = 0; m < H; ++m)
            acc += emb[e * H + m] * fus_W1[(size_t)(2 * H + m) * H + j];
        C2[e * H + j] = acc;
    } else {
        float acc = fus_b1[j];
        #pragma unroll 8
        for (int m = 0; m < H; ++m)
            acc += temp_b[m] * fus_W1[(size_t)(H + m) * H + j];
        beff[j] = acc;
    }
}

// ---------------------------------------------------------------------------
// prep_frag: pack weights into MFMA B-fragment order, bf16.
// Blob: kstep s (49) x chunk c (1024) x 8 bf16; c = nt*64+l ->
// W col = nt*16+(l&15), k_in_step = 8*(l>>4)+i.
// s0..7 fus_W1 clause part (logical K), s8 C1 (logical), s9..16 fus_W2 (pi2),
// s17..32 deriv_W[0], s33..48 deriv_W[1] (pi2 within each 256-half).
// ---------------------------------------------------------------------------
__global__ __launch_bounds__(256) void prep_frag(
    const float* __restrict__ fus_W1, const float* __restrict__ C1,
    const float* __restrict__ fus_W2, const float* __restrict__ deriv_W,
    u16* __restrict__ wblob)
{
    int s = blockIdx.x;
    #pragma unroll
    for (int it = 0; it < 4; ++it) {
        int c = it * 256 + threadIdx.x;
        int l = c & 63, nt = c >> 6;
        int ncol = (nt << 4) | (l & 15);
        int kin = (l >> 4) << 3;
        short8 v;
        #pragma unroll
        for (int i = 0; i < 8; ++i) {
            const float* srcp;
            if (s < 8) {
                srcp = fus_W1 + (size_t)(s * 32 + kin + i) * H;
            } else if (s == 8) {
                srcp = C1 + (size_t)(kin + i) * H;
            } else if (s < 17) {
                int k = (s - 9) * 32 + kin + i;
                srcp = fus_W2 + (size_t)pi2(k) * H;
            } else if (s < 33) {
                int k = (s - 17) * 32 + kin + i;
                srcp = deriv_W + (size_t)((k >> 8) * 256 + pi2(k & 255)) * H;
            } else {
                int k = (s - 33) * 32 + kin + i;
                srcp = deriv_W + (size_t)(512 + (k >> 8) * 256 + pi2(k & 255)) * H;
            }
            v[i] = (short)f2bf(srcp[ncol]);
        }
        *reinterpret_cast<short8*>(wblob + (size_t)s * 8192 + (size_t)c * 8) = v;
    }
}

// ---------------------------------------------------------------------------
// CSR build
// ---------------------------------------------------------------------------
__global__ void count_kernel(const int* __restrict__ dst, int* __restrict__ cnt)
{
    int e = blockIdx.x * blockDim.x + threadIdx.x;
    if (e < N_EDGES) atomicAdd(&cnt[dst[e]], 1);
}

__global__ __launch_bounds__(1024) void scan1_kernel(
    const int* __restrict__ cnt, int* __restrict__ off, int* __restrict__ bsum)
{
    __shared__ int s[1024];
    int i = blockIdx.x * 1024 + threadIdx.x;
    int v = (i < N_NODES) ? cnt[i] : 0;
    s[threadIdx.x] = v;
    __syncthreads();
    #pragma unroll
    for (int o = 1; o < 1024; o <<= 1) {
        int t = (threadIdx.x >= o) ? s[threadIdx.x - o] : 0;
        __syncthreads();
        s[threadIdx.x] += t;
        __syncthreads();
    }
    if (i < N_NODES) off[i] = s[threadIdx.x];
    if (threadIdx.x == 1023) bsum[blockIdx.x] = s[1023];
}

__global__ void scan2_kernel(const int* __restrict__ bsum, int* __restrict__ bbase)
{
    if (threadIdx.x == 0) {
        int acc = 0;
        for (int b = 0; b < SCAN_G; ++b) { bbase[b] = acc; acc += bsum[b]; }
    }
}

__global__ __launch_bounds__(1024) void scan3_kernel(
    int* __restrict__ off, const int* __restrict__ bbase,
    const int* __restrict__ cnt, int* __restrict__ cursor)
{
    int i = blockIdx.x * 1024 + threadIdx.x;
    if (i < N_NODES) {
        int incl = off[i] + bbase[blockIdx.x];
        off[i] = incl;
        cursor[i] = incl - cnt[i];
    }
}

__global__ void fill_kernel(const int* __restrict__ src, const int* __restrict__ dst,
                            int* __restrict__ cursor, int* __restrict__ csr)
{
    int e = blockIdx.x * blockDim.x + threadIdx.x;
    if (e < N_EDGES) {
        int pos = atomicAdd(&cursor[dst[e]], 1);
        csr[pos] = src[e];
    }
}

// ---------------------------------------------------------------------------
// gather: one wave per node, half-wave per edge-stream
// ---------------------------------------------------------------------------
__global__ __launch_bounds__(256) void gather_kernel(
    const u16* __restrict__ xb, const int* __restrict__ csr,
    const int* __restrict__ off, const int* __restrict__ cnt,
    u16* __restrict__ agg)
{
    int node = blockIdx.x * 4 + (threadIdx.x >> 6);
    int l = threadIdx.x & 63;
    int half = l >> 5, lc = l & 31;
    int deg = cnt[node];
    int start = off[node] - deg;
    float a[8] = {0.f, 0.f, 0.f, 0.f, 0.f, 0.f, 0.f, 0.f};
    int j = half;
    for (; j + 2 < deg; j += 4) {
        int s0 = csr[start + j];
        int s1 = csr[start + j + 2];
        short8 v0 = *reinterpret_cast<const short8*>(xb + (size_t)s0 * H + lc * 8);
        short8 v1 = *reinterpret_cast<const short8*>(xb + (size_t)s1 * H + lc * 8);
        #pragma unroll
        for (int i = 0; i < 8; ++i)
            a[i] += bf2f((u16)v0[i]) + bf2f((u16)v1[i]);
    }
    if (j < deg) {
        int s0 = csr[start + j];
        short8 v0 = *reinterpret_cast<const short8*>(xb + (size_t)s0 * H + lc * 8);
        #pragma unroll
        for (int i = 0; i < 8; ++i)
            a[i] += bf2f((u16)v0[i]);
    }
    #pragma unroll
    for (int i = 0; i < 8; ++i)
        a[i] += __shfl_xor(a[i], 32);
    if (half == 0) {
        float sc = 1.0f / fmaxf((float)deg, 1.0f);
        short8 o;
        #pragma unroll
        for (int i = 0; i < 8; ++i) o[i] = (short)f2bf(a[i] * sc);
        *reinterpret_cast<short8*>(agg + (size_t)node * H + lc * 8) = o;
    }
}

// ---------------------------------------------------------------------------
// 8-wave GEMM helpers: BM=128, BN=256, BK=32; wave (wm=w>>2, wn=w&3)
// ---------------------------------------------------------------------------
__device__ __forceinline__ void stageA8(u16* Af, const u16* __restrict__ src,
                                        int i0, int kbase, int tid)
{
    int rt = tid >> 6, l = tid & 63;
    int row = min(i0 + rt * 16 + (l & 15), N_NODES - 1);
    gload16(src + (size_t)row * H + kbase + ((l >> 4) << 3), Af + (tid << 3));
}

__device__ __forceinline__ void stageB8(u16* Bf, const u16* __restrict__ wk, int tid)
{
    gload16(wk + ((size_t)tid << 3),         Bf + (tid << 3));
    gload16(wk + ((size_t)(tid + 512) << 3), Bf + ((tid + 512) << 3));
}

__device__ __forceinline__ void mfma_step8(const u16* Af, const u16* Bf,
                                           int wm, int wn, int l, f32x4 acc[4][4])
{
    short8 a[4], b[4];
    #pragma unroll
    for (int m = 0; m < 4; ++m)
        a[m] = *reinterpret_cast<const short8*>(Af + ((((wm << 2) | m) << 6 | l) << 3));
    #pragma unroll
    for (int n = 0; n < 4; ++n)
        b[n] = *reinterpret_cast<const short8*>(Bf + ((((wn << 2) | n) << 6 | l) << 3));
    __builtin_amdgcn_s_setprio(1);
    #pragma unroll
    for (int n = 0; n < 4; ++n)
        #pragma unroll
        for (int m = 0; m < 4; ++m)
            acc[m][n] = __builtin_amdgcn_mfma_f32_16x16x32_bf16(a[m], b[n],
                                                                acc[m][n], 0, 0, 0);
    __builtin_amdgcn_s_setprio(0);
}

// ---------------------------------------------------------------------------
// K1: h = relu(clause@W1a + pe@C1 + C2[type] + beff); h sigma-ordered bf16.
// 2-deep pipeline, counted vmcnt; pe fragment computed in prologue regs,
// ds_written into Af[0] at t=8 (Af[0] is dead after t=6's read-release).
// ---------------------------------------------------------------------------
__global__ __launch_bounds__(512, 4) void k1_mfma(
    const u16* __restrict__ cb, const float* __restrict__ ts,
    const int* __restrict__ types, const u16* __restrict__ wblob,
    const float* __restrict__ C2, const float* __restrict__ beff,
    u16* __restrict__ hb)
{
    __shared__ __align__(16) u16 Af[2][4096];
    __shared__ __align__(16) u16 Bf[2][8192];
    int tid = threadIdx.x, w = tid >> 6, l = tid & 63;
    int wm = w >> 2, wn = w & 3, g = l >> 4, c0 = l & 15;
    int kg = g << 3;
    int i0 = blockIdx.x * 128;
    f32x4 acc[4][4] = {};

    // pe fragment for row (w*16+c0), k = kg..kg+7 (one frag per thread)
    short8 pv;
    {
        float tsv = ts[min(i0 + ((w << 4) | c0), N_NODES - 1)];
        #pragma unroll
        for (int i = 0; i < 8; ++i) {
            int k = kg + i;
            float fr = expf(-0.57564627324851f * (float)(k & 15));
            float ang = tsv * fr;
            pv[i] = (short)f2bf((k < 16) ? sinf(ang) : cosf(ang));
        }
    }

    stageA8(Af[0], cb, i0, 0, tid);
    stageB8(Bf[0], wblob, tid);
    #pragma unroll
    for (int t = 0; t < 9; ++t) {
        int cur = t & 1;
        if (t < 8) {
            if (t < 7) stageA8(Af[cur ^ 1], cb, i0, (t + 1) * 32, tid);
            stageB8(Bf[cur ^ 1], wblob + (size_t)(t + 1) * 8192, tid);
        }
        if (t == 8)
            *reinterpret_cast<short8*>(Af[0] + (tid << 3)) = pv;
        if (t < 7)       BAR_WAIT3();
        else if (t == 7) BAR_WAIT2();
        else             BAR_WAIT0L();
        mfma_step8(Af[cur], Bf[cur], wm, wn, l, acc);
        BAR_REL();
    }

    float bev[4];
    #pragma unroll
    for (int n = 0; n < 4; ++n) bev[n] = beff[(((wn << 2) | n) << 4) | c0];
    #pragma unroll
    for (int m = 0; m < 4; ++m) {
        #pragma unroll
        for (int r = 0; r < 4; ++r) {
            int rl = (((wm << 2) | m) << 4) + (g << 2) + r;
            int row = i0 + rl;
            bool ok = row < N_NODES;
            int tp = types[ok ? row : 0];
            const float* c2r = C2 + (size_t)tp * H;
            ushort4 o;
            float v0 = fmaxf(acc[m][0][r] + bev[0] + c2r[((wn << 2) << 4) | c0], 0.f);
            float v1 = fmaxf(acc[m][1][r] + bev[1] + c2r[(((wn << 2) | 1) << 4) | c0], 0.f);
            float v2 = fmaxf(acc[m][2][r] + bev[2] + c2r[(((wn << 2) | 2) << 4) | c0], 0.f);
            float v3 = fmaxf(acc[m][3][r] + bev[3] + c2r[(((wn << 2) | 3) << 4) | c0], 0.f);
            o.x = f2bf(v0); o.y = f2bf(v1); o.z = f2bf(v2); o.w = f2bf(v3);
            if (ok)
                *reinterpret_cast<ushort4*>(hb + (size_t)row * H + (wn << 6) + (c0 << 2)) = o;
        }
    }
}

// ---------------------------------------------------------------------------
// K2: xb = bf16(LN(h@W2 + b2 + clause) * g + b); in-place hb==xb allowed.
// ---------------------------------------------------------------------------
__global__ __launch_bounds__(512, 4) void k2_mfma(
    const u16* __restrict__ hb, const u16* __restrict__ cb,
    const u16* __restrict__ wblob, const float* __restrict__ b2,
    const float* __restrict__ gW, const float* __restrict__ bW,
    u16* __restrict__ xb)
{
    __shared__ __align__(16) u16 Af[2][4096];
    __shared__ __align__(16) u16 Bf[2][8192];
    __shared__ float2 red[512];
    int tid = threadIdx.x, w = tid >> 6, l = tid & 63;
    int wm = w >> 2, wn = w & 3, g = l >> 4, c0 = l & 15;
    int i0 = blockIdx.x * 128;
    f32x4 acc[4][4] = {};

    stageA8(Af[0], hb, i0, 0, tid);
    stageB8(Bf[0], wblob, tid);
    #pragma unroll
    for (int t = 0; t < 8; ++t) {
        int cur = t & 1;
        if (t < 7) {
            stageA8(Af[cur ^ 1], hb, i0, (t + 1) * 32, tid);
            stageB8(Bf[cur ^ 1], wblob + (size_t)(t + 1) * 8192, tid);
        }
        if (t < 7) BAR_WAIT3(); else BAR_WAIT0();
        mfma_step8(Af[cur], Bf[cur], wm, wn, l, acc);
        BAR_REL();
    }

    float bv[4], gv[4], bbv[4];
    int lc[4];
    #pragma unroll
    for (int n = 0; n < 4; ++n) {
        lc[n] = (((wn << 2) | n) << 4) | c0;
        bv[n] = b2[lc[n]]; gv[n] = gW[lc[n]]; bbv[n] = bW[lc[n]];
    }
    #pragma unroll
    for (int m = 0; m < 4; ++m) {
        #pragma unroll
        for (int r = 0; r < 4; ++r) {
            int rl = (((wm << 2) | m) << 4) + (g << 2) + r;
            int rowc = min(i0 + rl, N_NODES - 1);
            const u16* cr = cb + (size_t)rowc * H;   // logical order
            float s = 0.f, q = 0.f;
            #pragma unroll
            for (int n = 0; n < 4; ++n) {
                float pv = acc[m][n][r] + bv[n] + bf2f(cr[lc[n]]);
                acc[m][n][r] = pv;
                s += pv; q += pv * pv;
            }
            #pragma unroll
            for (int o = 1; o < 16; o <<= 1) {
                s += __shfl_xor(s, o);
                q += __shfl_xor(q, o);
            }
            if (c0 == 0) red[(rl << 2) | wn] = make_float2(s, q);
        }
    }
    __syncthreads();
    #pragma unroll
    for (int m = 0; m < 4; ++m) {
        #pragma unroll
        for (int r = 0; r < 4; ++r) {
            int rl = (((wm << 2) | m) << 4) + (g << 2) + r;
            int row = i0 + rl;
            float2 t0 = red[(rl << 2) | 0], t1 = red[(rl << 2) | 1];
            float2 t2 = red[(rl << 2) | 2], t3 = red[(rl << 2) | 3];
            float S = t0.x + t1.x + t2.x + t3.x;
            float Q = t0.y + t1.y + t2.y + t3.y;
            float mu = S * (1.0f / 256.0f);
            float rstd = rsqrtf(Q * (1.0f / 256.0f) - mu * mu + 1e-5f);
            if (row < N_NODES) {
                ushort4 o;
                o.x = f2bf((acc[m][0][r] - mu) * rstd * gv[0] + bbv[0]);
                o.y = f2bf((acc[m][1][r] - mu) * rstd * gv[1] + bbv[1]);
                o.z = f2bf((acc[m][2][r] - mu) * rstd * gv[2] + bbv[2]);
                o.w = f2bf((acc[m][3][r] - mu) * rstd * gv[3] + bbv[3]);
                *reinterpret_cast<ushort4*>(xb + (size_t)row * H + (wn << 6) + (c0 << 2)) = o;
            }
        }
    }
}

// ---------------------------------------------------------------------------
// K5: x' = LN(x + relu([x|agg]@Wl + bl))*g + b; in-place on xb.
// FINAL writes fp32 d_out in logical column order.
// ---------------------------------------------------------------------------
template<bool FINAL>
__global__ __launch_bounds__(512, 4) void k5_mfma(
    const u16* __restrict__ xb, const u16* __restrict__ aggb,
    const u16* __restrict__ wblob, const float* __restrict__ bl,
    const float* __restrict__ gl_, const float* __restrict__ bnl,
    u16* __restrict__ xbout, float* __restrict__ xout)
{
    __shared__ __align__(16) u16 Af[2][4096];
    __shared__ __align__(16) u16 Bf[2][8192];
    __shared__ float2 red[512];
    int tid = threadIdx.x, w = tid >> 6, l = tid & 63;
    int wm = w >> 2, wn = w & 3, g = l >> 4, c0 = l & 15;
    int i0 = blockIdx.x * 128;
    f32x4 acc[4][4] = {};

    stageA8(Af[0], xb, i0, 0, tid);
    stageB8(Bf[0], wblob, tid);
    #pragma unroll
    for (int t = 0; t < 16; ++t) {
        int cur = t & 1;
        if (t < 15) {
            int t1 = t + 1;
            stageA8(Af[cur ^ 1], (t1 < 8) ? xb : aggb, i0, (t1 & 7) * 32, tid);
            stageB8(Bf[cur ^ 1], wblob + (size_t)t1 * 8192, tid);
        }
        if (t < 15) BAR_WAIT3(); else BAR_WAIT0();
        mfma_step8(Af[cur], Bf[cur], wm, wn, l, acc);
        BAR_REL();
    }

    float bv[4], gv[4], bbv[4];
    int lc[4];
    #pragma unroll
    for (int n = 0; n < 4; ++n) {
        lc[n] = (((wn << 2) | n) << 4) | c0;
        bv[n] = bl[lc[n]]; gv[n] = gl_[lc[n]]; bbv[n] = bnl[lc[n]];
    }
    #pragma unroll
    for (int m = 0; m < 4; ++m) {
        #pragma unroll
        for (int r = 0; r < 4; ++r) {
            int rl = (((wm << 2) | m) << 4) + (g << 2) + r;
            int rowc = min(i0 + rl, N_NODES - 1);
            ushort4 xr = *reinterpret_cast<const ushort4*>(
                xb + (size_t)rowc * H + (wn << 6) + (c0 << 2));
            float p0 = bf2f(xr.x) + fmaxf(acc[m][0][r] + bv[0], 0.f);
            float p1 = bf2f(xr.y) + fmaxf(acc[m][1][r] + bv[1], 0.f);
            float p2 = bf2f(xr.z) + fmaxf(acc[m][2][r] + bv[2], 0.f);
            float p3 = bf2f(xr.w) + fmaxf(acc[m][3][r] + bv[3], 0.f);
            acc[m][0][r] = p0; acc[m][1][r] = p1;
            acc[m][2][r] = p2; acc[m][3][r] = p3;
            float s = p0 + p1 + p2 + p3;
            float q = p0 * p0 + p1 * p1 + p2 * p2 + p3 * p3;
            #pragma unroll
            for (int o = 1; o < 16; o <<= 1) {
                s += __shfl_xor(s, o);
                q += __shfl_xor(q, o);
            }
            if (c0 == 0) red[(rl << 2) | wn] = make_float2(s, q);
        }
    }
    __syncthreads();
    #pragma unroll
    for (int m = 0; m < 4; ++m) {
        #pragma unroll
        for (int r = 0; r < 4; ++r) {
            int rl = (((wm << 2) | m) << 4) + (g << 2) + r;
            int row = i0 + rl;
            float2 t0 = red[(rl << 2) | 0], t1 = red[(rl << 2) | 1];
            float2 t2 = red[(rl << 2) | 2], t3 = red[(rl << 2) | 3];
            float S = t0.x + t1.x + t2.x + t3.x;
            float Q = t0.y + t1.y + t2.y + t3.y;
            float mu = S * (1.0f / 256.0f);
            float rstd = rsqrtf(Q * (1.0f / 256.0f) - mu * mu + 1e-5f);
            if (row < N_NODES) {
                if (FINAL) {
                    #pragma unroll
                    for (int n = 0; n < 4; ++n)
                        xout[(size_t)row * H + lc[n]] =
                            (acc[m][n][r] - mu) * rstd * gv[n] + bbv[n];
                } else {
                    ushort4 o;
                    o.x = f2bf((acc[m][0][r] - mu) * rstd * gv[0] + bbv[0]);
                    o.y = f2bf((acc[m][1][r] - mu) * rstd * gv[1] + bbv[1]);
                    o.z = f2bf((acc[m][2][r] - mu) * rstd * gv[2] + bbv[2]);
                    o.w = f2bf((acc[m][3][r] - mu) * rstd * gv[3] + bbv[3]);
                    *reinterpret_cast<ushort4*>(
                        xbout + (size_t)row * H + (wn << 6) + (c0 << 2)) = o;
                }
            }
        }
    }
}

// ---------------------------------------------------------------------------
extern "C" void kernel_launch(void* const* d_in, const int* in_sizes, int n_in,
                              void* d_out, int out_size, void* d_ws, size_t ws_size,
                              hipStream_t stream)
{
    const float* clause  = (const float*)d_in[0];
    const float* ts      = (const float*)d_in[1];
    const int*   types   = (const int*)  d_in[2];
    const int*   edges   = (const int*)  d_in[3];
    const float* emb     = (const float*)d_in[4];
    const float* temp_W  = (const float*)d_in[5];
    const float* temp_b  = (const float*)d_in[6];
    const float* fus_W1  = (const float*)d_in[7];
    const float* fus_b1  = (const float*)d_in[8];
    const float* fus_W2  = (const float*)d_in[9];
    const float* fus_b2  = (const float*)d_in[10];
    const float* in_g    = (const float*)d_in[11];
    const float* in_b    = (const float*)d_in[12];
    const float* deriv_W = (const float*)d_in[13];
    const float* deriv_b = (const float*)d_in[14];
    const float* dn_g    = (const float*)d_in[15];
    const float* dn_b    = (const float*)d_in[16];

    char* p = (char*)d_ws;
    float* C1   = (float*)p;            p += 32 * H * 4;
    float* C2   = (float*)p;            p += NTYPES * H * 4;
    float* beff = (float*)p;            p += H * 4;
    int* cnt    = (int*)p;              p += N_NODES * 4;
    int* off    = (int*)p;              p += N_NODES * 4;
    int* cursor = (int*)p;              p += N_NODES * 4;
    int* bsum   = (int*)p;              p += 128 * 4;
    int* bbase  = (int*)p;              p += 128 * 4;
    int* csr    = (int*)p;              p += N_EDGES * 4;
    u16* wblob  = (u16*)p;              p += 49 * 8192 * 2;
    u16* B1     = (u16*)p;              p += (size_t)N_NODES * H * 2;  // clause_bf / agg
    u16* B2     = (u16*)p;              p += (size_t)N_NODES * H * 2;  // h / xb
    float* x    = (float*)d_out;

    const int* src = edges;
    const int* dst = edges + N_EDGES;

    conv_bf16<<<(N_NODES * H / 8 + 255) / 256, 256, 0, stream>>>(clause, B1);
    prep_small<<<32 + NTYPES + 1, 256, 0, stream>>>(temp_W, temp_b, emb, fus_W1,
                                                    fus_b1, C1, C2, beff);
    prep_frag<<<49, 256, 0, stream>>>(fus_W1, C1, fus_W2, deriv_W, wblob);

    hipMemsetAsync(cnt, 0, N_NODES * sizeof(int), stream);
    count_kernel<<<(N_EDGES + 255) / 256, 256, 0, stream>>>(dst, cnt);
    scan1_kernel<<<SCAN_G, 1024, 0, stream>>>(cnt, off, bsum);
    scan2_kernel<<<1, 64, 0, stream>>>(bsum, bbase);
    scan3_kernel<<<SCAN_G, 1024, 0, stream>>>(off, bbase, cnt, cursor);
    fill_kernel<<<(N_EDGES + 255) / 256, 256, 0, stream>>>(src, dst, cursor, csr);

    k1_mfma<<<GRID5, 512, 0, stream>>>(B1, ts, types, wblob, C2, beff, B2);
    k2_mfma<<<GRID5, 512, 0, stream>>>(B2, B1, wblob + (size_t)9 * 8192,
                                       fus_b2, in_g, in_b, B2);

    // layer 0 (bf16 in-place on B2; B1 becomes agg)
    gather_kernel<<<N_NODES / 4, 256, 0, stream>>>(B2, csr, off, cnt, B1);
    k5_mfma<false><<<GRID5, 512, 0, stream>>>(
        B2, B1, wblob + (size_t)17 * 8192, deriv_b, dn_g, dn_b, B2, nullptr);
    // layer 1 (writes fp32 d_out, logical order)
    gather_kernel<<<N_NODES / 4, 256, 0, stream>>>(B2, csr, off, cnt, B1);
    k5_mfma<true><<<GRID5, 512, 0, stream>>>(
        B2, B1, wblob + (size_t)33 * 8192, deriv_b + H, dn_g + H, dn_b + H,
        nullptr, x);
}